// Round 8
// baseline (50.558 us; speedup 1.0000x reference)
//
#include <hip/hip_runtime.h>

// Basket embedding mean-pool.
// item_ids: [B, L, M] int32; basket_lens: [B, L] int32; emb: [VOCAB, H] f32
// out: [B, L, H] f32 ; out[b,l,:] = sum_{m<len} emb[ids[b,l,m]] / max(len,1)
//
// R8: wave-per-basket compaction. Model from R2-R7 A/Bs: gather cost ~
// 15cy/segment with ~4-segment (59cy) floor per instruction; R5 pays the
// floor on ~half-padded instructions (20 issued, avg len 10.24). Here one
// wave owns one basket: len/ids are wave-uniform (readfirstlane -> SGPR,
// s_load ids), 64 lanes = 4 items x 16 channel-lanes, so each gather instr
// carries exactly 4 VALID 256B rows; iterations with 4t >= len issue
// nothing (execz). Chip-wide gather instrs: sum(ceil(len/4)) ~146K vs
// R5's 256K, all segments active. shfl_xor reduce across item sub-slots.

constexpr int Bn = 1024, Ln = 50, Mn = 20, Hn = 64;
constexpr int NB = Bn * Ln;                 // 51200 baskets

typedef float f32x4 __attribute__((ext_vector_type(4)));

__global__ __launch_bounds__(256) void basket_pool_wave_kernel(
    const int* __restrict__ item_ids,       // [NB, M]
    const int* __restrict__ basket_lens,    // [NB]
    const float* __restrict__ emb,          // [VOCAB, H]
    float* __restrict__ out)                // [NB, H]
{
    const int lane = threadIdx.x & 63;
    int basket = blockIdx.x * 4 + (threadIdx.x >> 6);   // wave id -> basket
    basket = __builtin_amdgcn_readfirstlane(basket);    // force SGPR/uniform
    if (basket >= NB) return;

    const int len = __builtin_amdgcn_readfirstlane(basket_lens[basket]);
    const int* __restrict__ ids = item_ids + basket * Mn;

    // wave-uniform id preload -> scalar loads (SGPRs), zero VMEM segments
    int s[Mn];
#pragma unroll
    for (int m = 0; m < Mn; ++m) s[m] = ids[m];

    const int g  = lane >> 4;          // item sub-slot 0..3
    const int j4 = (lane & 15) << 2;   // channel offset (4 floats/lane)

    f32x4 acc = {0.f, 0.f, 0.f, 0.f};
#pragma unroll
    for (int t = 0; t < 5; ++t) {
        // per-lane id among s[4t..4t+3] (compile-time indices, cndmask select)
        int idv = s[4 * t + 0];
        idv = (g == 1) ? s[4 * t + 1] : idv;
        idv = (g == 2) ? s[4 * t + 2] : idv;
        idv = (g == 3) ? s[4 * t + 3] : idv;
        if (4 * t + g < len) {         // whole-wave inactive -> execz skip
            const f32x4 v = *reinterpret_cast<const f32x4*>(
                emb + (idv * Hn + j4));
            acc += v;
        }
    }

    // reduce across the 4 item sub-slots (lane bits 4-5)
    acc.x += __shfl_xor(acc.x, 16, 64);
    acc.y += __shfl_xor(acc.y, 16, 64);
    acc.z += __shfl_xor(acc.z, 16, 64);
    acc.w += __shfl_xor(acc.w, 16, 64);
    acc.x += __shfl_xor(acc.x, 32, 64);
    acc.y += __shfl_xor(acc.y, 32, 64);
    acc.z += __shfl_xor(acc.z, 32, 64);
    acc.w += __shfl_xor(acc.w, 32, 64);

    const float inv = 1.0f / (float)(len > 0 ? len : 1);
    if (g == 0) {                      // 16 lanes -> one 256B store
        *reinterpret_cast<f32x4*>(out + (basket * Hn + j4)) = acc * inv;
    }
}

extern "C" void kernel_launch(void* const* d_in, const int* in_sizes, int n_in,
                              void* d_out, int out_size, void* d_ws, size_t ws_size,
                              hipStream_t stream) {
    const int*   item_ids    = (const int*)d_in[0];    // B*L*M
    const int*   basket_lens = (const int*)d_in[1];    // B*L
    const float* emb         = (const float*)d_in[2];  // VOCAB*H
    float*       out         = (float*)d_out;          // B*L*H

    const int grid = NB / 4;                           // 4 waves (baskets)/block
    basket_pool_wave_kernel<<<grid, 256, 0, stream>>>(
        item_ids, basket_lens, emb, out);
}

// Round 9
// 25.178 us; speedup vs baseline: 2.0080x; 2.0080x over previous
//
#include <hip/hip_runtime.h>

// Basket embedding mean-pool.
// item_ids: [B, L, M] int32; basket_lens: [B, L] int32; emb: [VOCAB, H] f32
// out: [B, L, H] f32 ; out[b,l,:] = sum_{m<len} emb[ids[b,l,m]] / max(len,1)
//
// R9: R5 burst structure + wave-uniform trip count. Surviving bottleneck
// model: per-CU VMEM instruction issue (~59cy/instr). R5 issues fixed 20
// gathers/wave; actual need is ceil(max len over the wave's 4 baskets / 4)
// (avg 4.4 of 5 blocks -> -12% gather instrs). T computed via 2 shfl_xor
// max + readfirstlane -> scalar if-chain of 4-gather bursts (no exec mask,
// no LDS, no extra launches). Padded slots within an active block still use
// the dup-id0 trick (proven free, R4). nt-STORE only (R6 proved nt loads
// regress; nt store untested alone): output is never re-read, keep it from
// evicting table lines in L2.

constexpr int Bn = 1024, Ln = 50, Mn = 20, Hn = 64;
constexpr int NB = Bn * Ln;                 // 51200 baskets

typedef float f32x4 __attribute__((ext_vector_type(4)));

__global__ __launch_bounds__(256) void basket_pool_kernel(
    const int* __restrict__ item_ids,       // [NB, M]
    const int* __restrict__ basket_lens,    // [NB]
    const float* __restrict__ emb,          // [VOCAB, H]
    float* __restrict__ out)                // [NB, H]
{
    const int tid    = blockIdx.x * blockDim.x + threadIdx.x;
    const int basket = tid >> 4;            // 16 lanes per basket, 4/wave
    const int lane4  = (tid & 15) << 2;     // channel offset (4 floats)
    if (basket >= NB) return;

    const int len = basket_lens[basket];

    // wave-uniform trip count T = max over the wave's 4 baskets of ceil(len/4)
    int t4 = (len + 3) >> 2;
    t4 = max(t4, __shfl_xor(t4, 16, 64));
    t4 = max(t4, __shfl_xor(t4, 32, 64));
    const int T = __builtin_amdgcn_readfirstlane(t4);   // SGPR -> s_branch

    const int* __restrict__ ids = item_ids + basket * Mn;

    // id preload: 4 int4 always, 5th only if some basket needs items 16..19
    int idb[Mn];
#pragma unroll
    for (int c = 0; c < 4; ++c) {
        const int4 t = reinterpret_cast<const int4*>(ids)[c];
        idb[c * 4 + 0] = t.x; idb[c * 4 + 1] = t.y;
        idb[c * 4 + 2] = t.z; idb[c * 4 + 3] = t.w;
    }
    if (T > 4) {
        const int4 t = reinterpret_cast<const int4*>(ids)[4];
        idb[16] = t.x; idb[17] = t.y; idb[18] = t.z; idb[19] = t.w;
    } else {
        idb[16] = idb[17] = idb[18] = idb[19] = idb[0];
    }
    const int id0 = idb[0];                 // always a valid vocab id

    // burst loads: T blocks of 4 gathers, all issued before consumption
    f32x4 v[Mn];
#define LOAD_BLK(B_)                                                     \
    {                                                                    \
        _Pragma("unroll")                                                \
        for (int m = 4 * (B_); m < 4 * (B_) + 4; ++m) {                  \
            const int e = (m < len) ? idb[m] : id0;  /* dup -> merged */ \
            v[m] = *reinterpret_cast<const f32x4*>(emb + (e * Hn + lane4)); \
        }                                                                \
    }
    if (T > 0) LOAD_BLK(0)
    if (T > 1) LOAD_BLK(1)
    if (T > 2) LOAD_BLK(2)
    if (T > 3) LOAD_BLK(3)
    if (T > 4) LOAD_BLK(4)
#undef LOAD_BLK

    // masked accumulate, 4 independent chains, ascending (consume oldest first)
    f32x4 a0 = {0.f, 0.f, 0.f, 0.f};
    f32x4 a1 = {0.f, 0.f, 0.f, 0.f};
    f32x4 a2 = {0.f, 0.f, 0.f, 0.f};
    f32x4 a3 = {0.f, 0.f, 0.f, 0.f};
#define ACC_BLK(B_)                                                      \
    {                                                                    \
        const int mb = 4 * (B_);                                         \
        a0 += v[mb + 0] * ((mb + 0 < len) ? 1.f : 0.f);                  \
        a1 += v[mb + 1] * ((mb + 1 < len) ? 1.f : 0.f);                  \
        a2 += v[mb + 2] * ((mb + 2 < len) ? 1.f : 0.f);                  \
        a3 += v[mb + 3] * ((mb + 3 < len) ? 1.f : 0.f);                  \
    }
    if (T > 0) ACC_BLK(0)
    if (T > 1) ACC_BLK(1)
    if (T > 2) ACC_BLK(2)
    if (T > 3) ACC_BLK(3)
    if (T > 4) ACC_BLK(4)
#undef ACC_BLK

    const float inv = 1.0f / (float)(len > 0 ? len : 1);
    const f32x4 r = (a0 + a1 + a2 + a3) * inv;   // T==0 wave stores zeros

    __builtin_nontemporal_store(
        r, reinterpret_cast<f32x4*>(out + (basket * Hn + lane4)));
}

extern "C" void kernel_launch(void* const* d_in, const int* in_sizes, int n_in,
                              void* d_out, int out_size, void* d_ws, size_t ws_size,
                              hipStream_t stream) {
    const int*   item_ids    = (const int*)d_in[0];    // B*L*M
    const int*   basket_lens = (const int*)d_in[1];    // B*L
    const float* emb         = (const float*)d_in[2];  // VOCAB*H
    float*       out         = (float*)d_out;          // B*L*H

    const int total_threads = NB * 16;                 // 819200
    const int block = 256;
    const int grid  = (total_threads + block - 1) / block;  // 3200
    basket_pool_kernel<<<grid, block, 0, stream>>>(item_ids, basket_lens, emb, out);
}